// Round 9
// baseline (214.792 us; speedup 1.0000x reference)
//
#include <hip/hip_runtime.h>
#include <stdint.h>

#define N_OUT_  4096
#define N_IN_   4096
#define BATCH_  4096
#define NNZ_    1600000

typedef unsigned short ushort_t;
typedef float  f32x16 __attribute__((ext_vector_type(16)));
typedef short  short8 __attribute__((ext_vector_type(8)));
typedef __bf16 bf16x8 __attribute__((ext_vector_type(8)));

// RNE f32 -> bf16
__device__ inline ushort_t f32_to_bf16(float f) {
  uint32_t u = __float_as_uint(f);
  uint32_t r = u + 0x7FFFu + ((u >> 16) & 1u);
  return (ushort_t)(r >> 16);
}
__device__ inline float bf16_to_f32(ushort_t h) {
  return __uint_as_float(((uint32_t)h) << 16);
}

// async global->LDS, 16B/lane; LDS dest wave-uniform base + lane*16 (linear)
__device__ inline void gload_lds16(const void* g, void* l) {
  __builtin_amdgcn_global_load_lds(
      (const __attribute__((address_space(1))) void*)g,
      (__attribute__((address_space(3))) void*)l,
      16, 0, 0);
}

// 32x32x16 bf16 MFMA: A row=lane&31 k0=(lane>>5)*8; C/D col=lane&31,
// row=(reg&3)+8*(reg>>2)+4*(lane>>5)  [C/D verified m74/m101]
__device__ inline f32x16 mfma32_bf16(short8 a, short8 b, f32x16 c) {
  return __builtin_amdgcn_mfma_f32_32x32x16_bf16(
      __builtin_bit_cast(bf16x8, a), __builtin_bit_cast(bf16x8, b), c, 0, 0, 0);
}

#define BARRIER() asm volatile("s_barrier" ::: "memory")
template <int N> __device__ __forceinline__ void waitvm() {
  if constexpr (N == 8)      asm volatile("s_waitcnt vmcnt(8)" ::: "memory");
  else if constexpr (N == 6) asm volatile("s_waitcnt vmcnt(6)" ::: "memory");
  else if constexpr (N == 4) asm volatile("s_waitcnt vmcnt(4)" ::: "memory");
  else                       asm volatile("s_waitcnt vmcnt(0)" ::: "memory");
}

// ------- 1. COO scatter-add directly into bf16 W via u32 CAS loop ----------
__global__ __launch_bounds__(256) void scatter_coo_cas(
    const float* __restrict__ vals, const int* __restrict__ rows,
    const int* __restrict__ cols, uint32_t* __restrict__ W32) {
  int i = blockIdx.x * 256 + threadIdx.x;
  if (i >= NNZ_) return;
  const size_t idx = (size_t)rows[i] * N_IN_ + cols[i];
  const float v = vals[i];
  uint32_t* p = &W32[idx >> 1];
  const bool hi = (idx & 1) != 0;
  uint32_t old = *p, assumed;
  do {
    assumed = old;
    ushort_t h = hi ? (ushort_t)(assumed >> 16) : (ushort_t)(assumed & 0xFFFFu);
    ushort_t nh = f32_to_bf16(bf16_to_f32(h) + v);
    uint32_t nw = hi ? ((assumed & 0x0000FFFFu) | ((uint32_t)nh << 16))
                     : ((assumed & 0xFFFF0000u) | (uint32_t)nh);
    old = atomicCAS(p, assumed, nw);
  } while (old != assumed);
}

// ------- 2. fused: memset Wb (blocks >= 16384) + transpose inputs ----------
#define TR_BLOCKS 16384   // (4096/32)^2
#define MS_BLOCKS 2048    // 2M uint4 = 32 MiB zeroed, 4 uint4/thread
__global__ __launch_bounds__(256) void prep_fused(
    const float* __restrict__ in, ushort_t* __restrict__ out,
    uint4* __restrict__ Wb4) {
  const int b = blockIdx.x;
  if (b < TR_BLOCKS) {
    __shared__ float tile[32][33];
    const int bx = (b & 127) * 32, by = (b >> 7) * 32;
    const int tx = threadIdx.x & 31, ty = threadIdx.x >> 5;
#pragma unroll
    for (int i = 0; i < 32; i += 8)
      tile[ty + i][tx] = in[(size_t)(by + ty + i) * BATCH_ + bx + tx];
    __syncthreads();
#pragma unroll
    for (int i = 0; i < 32; i += 8)
      out[(size_t)(bx + ty + i) * N_IN_ + by + tx] = f32_to_bf16(tile[tx][ty + i]);
  } else {
    const uint4 z = {0u, 0u, 0u, 0u};
    const int idx = (b - TR_BLOCKS) * 256 + threadIdx.x;
#pragma unroll
    for (int j = 0; j < 4; ++j) Wb4[idx + j * (MS_BLOCKS * 256)] = z;
  }
}

// ------- 3. 256x256 ring-4 GEMM, r5 schedule + 32x32x16 MFMA ---------------
// C[m][n] = relu(sum_k A[m][k]*Bt[n][k] + bias[m])
// Per tile (BK=32): {aH reads | stage h0 | vmcnt(6) | barrier |
//   8 MFMA (rb0-1) | RA next-tile AL/B reads | stage h1 | 8 MFMA (rb2-3) |
//   barrier}.  (r5's empirically-best schedule, MFMA shape swapped.)
#define BM 256
#define BN 256
#define BK 32
#define KTILES 128            // 4096/32
#define TILE_BYTES 32768      // A 16K + B 16K
#define B_OFF 16384

__global__ __launch_bounds__(512, 2) void gemm_bias_relu(
    const ushort_t* __restrict__ A,    // bf16 [N_OUT][N_IN]
    const ushort_t* __restrict__ Bt,   // bf16 [BATCH][N_IN]
    const float* __restrict__ bias,    // [N_OUT]
    float* __restrict__ C) {           // f32 [N_OUT][BATCH]
  __shared__ __align__(16) char smem[4 * TILE_BYTES];  // 128 KiB

  const int tid  = threadIdx.x;
  const int wid  = tid >> 6;
  const int lane = tid & 63;

  // T1: XCD swizzle (nwg=256, 8 XCDs, bijective)
  const int bid = blockIdx.x;
  const int swz = (bid & 7) * 32 + (bid >> 3);
  const int brow = (swz >> 4) * BM;
  const int bcol = (swz & 15) * BN;

  const int wr = wid >> 2;        // 0..1 -> rows wr*128..+128
  const int wc = wid & 3;         // 0..3 -> cols wc*64..+64
  const int ln31 = lane & 31;
  const int hi5  = lane >> 5;     // k-half selector

  // frag LDS byte offsets (T2 XOR swizzle bits7-8 -> bits4-5, involution).
  // A: rowblock rb (32 rows), k-step ks: idx rb*2+ks
  // B: colblock cb (32 cols of C = 32 rows of Bt), k-step ks: idx cb*2+ks
  int aoff[8], boff[4];
#pragma unroll
  for (int rb = 0; rb < 4; ++rb)
#pragma unroll
    for (int ks = 0; ks < 2; ++ks) {
      int off = (wr * 128 + rb * 32 + ln31) * 64 + ks * 32 + hi5 * 16;
      aoff[rb * 2 + ks] = off ^ (((off >> 7) & 3) << 4);
    }
#pragma unroll
  for (int cb = 0; cb < 2; ++cb)
#pragma unroll
    for (int ks = 0; ks < 2; ++ks) {
      int off = (wc * 64 + cb * 32 + ln31) * 64 + ks * 32 + hi5 * 16;
      boff[cb * 2 + ks] = off ^ (((off >> 7) & 3) << 4);
    }

  // staging (unchanged from r5): waves 0-3 -> A, 4-7 -> B; wave sw owns 1KB
  // chunks 4sw..4sw+3; pre-swizzled per-lane global source (rule #21)
  const bool isB = wid >= 4;
  const int sw = isB ? wid - 4 : wid;
  const int swzl = lane ^ ((lane >> 3) & 3);
  const int rowInChunk = swzl >> 2;
  const int kelem = (swzl & 3) * 8;
  const ushort_t* gsrc = isB ? Bt : A;
  const size_t laneRowBase =
      (size_t)((isB ? bcol : brow) + sw * 64 + rowInChunk) * N_IN_ + kelem;
  const int ldsOpBase = isB ? B_OFF : 0;

#define STAGE(c, t)                                                           \
  gload_lds16(gsrc + laneRowBase + (size_t)(c) * 16 * N_IN_ + (size_t)(t) * BK,\
              smem + ((t) & 3) * TILE_BYTES + ldsOpBase +                     \
                  (4 * sw + (c)) * 1024)

  f32x16 acc[4][2] = {};
  short8 aE[4], bE[4], aO[4], bO[4], aH[4];  // aH: intra-tile only (rb 2-3)

  // prologue: stage tiles 0,1,2; vmcnt(8) retires tile 0; barrier; preload
#pragma unroll
  for (int t = 0; t < 3; ++t) { STAGE(0, t); STAGE(1, t); STAGE(2, t); STAGE(3, t); }
  waitvm<8>();
  BARRIER();
#pragma unroll
  for (int j = 0; j < 4; ++j) {
    aE[j] = *(const short8*)(smem + aoff[j]);
    bE[j] = *(const short8*)(smem + B_OFF + boff[j]);
  }

#define CLUSTER(RB0, AF, BB)                                                  \
  do {                                                                        \
    __builtin_amdgcn_s_setprio(1);                                            \
    _Pragma("unroll") for (int rb = 0; rb < 2; ++rb)                          \
        _Pragma("unroll") for (int cb = 0; cb < 2; ++cb)                      \
            _Pragma("unroll") for (int ks = 0; ks < 2; ++ks)                  \
                acc[(RB0) + rb][cb] =                                         \
                    mfma32_bf16(AF[rb * 2 + ks], BB[cb * 2 + ks],             \
                                acc[(RB0) + rb][cb]);                         \
    __builtin_amdgcn_s_setprio(0);                                            \
  } while (0)

#define TILE(t, AL, BB, ALn, BBn, S_ON, VM, RA_ON)                            \
  do {                                                                        \
    const char* buf  = &smem[((t) & 3) * TILE_BYTES];                         \
    const char* bufn = &smem[(((t) + 1) & 3) * TILE_BYTES];                   \
    _Pragma("unroll") for (int j = 0; j < 4; ++j)                             \
        aH[j] = *(const short8*)(buf + aoff[j + 4]);                          \
    if (S_ON) { STAGE(0, (t) + 3); STAGE(1, (t) + 3); }                       \
    VM;                                                                       \
    BARRIER();                                                                \
    CLUSTER(0, AL, BB);                                                       \
    if (RA_ON) {                                                              \
      _Pragma("unroll") for (int j = 0; j < 4; ++j)                           \
          ALn[j] = *(const short8*)(bufn + aoff[j]);                          \
      _Pragma("unroll") for (int j = 0; j < 4; ++j)                           \
          BBn[j] = *(const short8*)(bufn + B_OFF + boff[j]);                  \
    }                                                                         \
    if (S_ON) { STAGE(2, (t) + 3); STAGE(3, (t) + 3); }                       \
    CLUSTER(2, aH, BB);                                                       \
    BARRIER();                                                                \
  } while (0)

  // main: tiles 0..123 in E/O pairs; peel 124-127 (stage stops, vmcnt 6/4/0)
  for (int t = 0; t < KTILES - 4; t += 2) {
    TILE(t,     aE, bE, aO, bO, 1, waitvm<6>(), 1);
    TILE(t + 1, aO, bO, aE, bE, 1, waitvm<6>(), 1);
  }
  TILE(KTILES - 4, aE, bE, aO, bO, 1, waitvm<6>(), 1);
  TILE(KTILES - 3, aO, bO, aE, bE, 0, waitvm<4>(), 1);
  TILE(KTILES - 2, aE, bE, aO, bO, 0, waitvm<0>(), 1);
  TILE(KTILES - 1, aO, bO, aE, bE, 0, (void)0,     0);

  // epilogue: C/D map col = lane&31, row = (reg&3) + 8*(reg>>2) + 4*hi5
#pragma unroll
  for (int rb = 0; rb < 4; ++rb) {
#pragma unroll
    for (int reg = 0; reg < 16; ++reg) {
      const int row = brow + wr * 128 + rb * 32 + (reg & 3) + 8 * (reg >> 2) + 4 * hi5;
      const float b = bias[row];
#pragma unroll
      for (int cb = 0; cb < 2; ++cb) {
        const int col = bcol + wc * 64 + cb * 32 + ln31;
        float v = acc[rb][cb][reg] + b;
        C[(size_t)row * BATCH_ + col] = v > 0.f ? v : 0.f;
      }
    }
  }
#undef TILE
#undef CLUSTER
#undef STAGE
}

extern "C" void kernel_launch(void* const* d_in, const int* in_sizes, int n_in,
                              void* d_out, int out_size, void* d_ws, size_t ws_size,
                              hipStream_t stream) {
  const float* inputs = (const float*)d_in[0];
  const float* values = (const float*)d_in[1];
  const float* biases = (const float*)d_in[2];
  const int*   rows   = (const int*)d_in[3];
  const int*   cols   = (const int*)d_in[4];
  float* out = (float*)d_out;

  // layout: [0,32M) bf16 W ; [32M,64M) bf16 in^T
  const size_t W_BF16_BYTES = (size_t)N_OUT_ * N_IN_ * 2;  // 32 MiB
  if (ws_size < 2 * W_BF16_BYTES) return;
  char* ws = (char*)d_ws;
  ushort_t* Wb = (ushort_t*)ws;
  ushort_t* Bt = (ushort_t*)(ws + W_BF16_BYTES);

  prep_fused<<<TR_BLOCKS + MS_BLOCKS, 256, 0, stream>>>(inputs, Bt, (uint4*)Wb);
  scatter_coo_cas<<<(NNZ_ + 255) / 256, 256, 0, stream>>>(values, rows, cols,
                                                          (uint32_t*)Wb);
  gemm_bias_relu<<<dim3(256), 512, 0, stream>>>(Wb, Bt, biases, out);
}

// Round 10
// 192.613 us; speedup vs baseline: 1.1151x; 1.1151x over previous
//
#include <hip/hip_runtime.h>
#include <stdint.h>

#define N_OUT_  4096
#define N_IN_   4096
#define BATCH_  4096
#define NNZ_    1600000

typedef unsigned short ushort_t;
typedef float  f32x4  __attribute__((ext_vector_type(4)));
typedef short  short8 __attribute__((ext_vector_type(8)));
typedef __bf16 bf16x8 __attribute__((ext_vector_type(8)));

// RNE f32 -> bf16
__device__ inline ushort_t f32_to_bf16(float f) {
  uint32_t u = __float_as_uint(f);
  uint32_t r = u + 0x7FFFu + ((u >> 16) & 1u);
  return (ushort_t)(r >> 16);
}
__device__ inline float bf16_to_f32(ushort_t h) {
  return __uint_as_float(((uint32_t)h) << 16);
}

// async global->LDS, 16B/lane; LDS dest wave-uniform base + lane*16 (linear)
__device__ inline void gload_lds16(const void* g, void* l) {
  __builtin_amdgcn_global_load_lds(
      (const __attribute__((address_space(1))) void*)g,
      (__attribute__((address_space(3))) void*)l,
      16, 0, 0);
}

__device__ inline f32x4 mfma_bf16(short8 a, short8 b, f32x4 c) {
  return __builtin_amdgcn_mfma_f32_16x16x32_bf16(
      __builtin_bit_cast(bf16x8, a), __builtin_bit_cast(bf16x8, b), c, 0, 0, 0);
}

#define BARRIER() asm volatile("s_barrier" ::: "memory")
template <int N> __device__ __forceinline__ void waitvm() {
  if constexpr (N == 8)      asm volatile("s_waitcnt vmcnt(8)" ::: "memory");
  else if constexpr (N == 6) asm volatile("s_waitcnt vmcnt(6)" ::: "memory");
  else if constexpr (N == 4) asm volatile("s_waitcnt vmcnt(4)" ::: "memory");
  else                       asm volatile("s_waitcnt vmcnt(0)" ::: "memory");
}

// ---------------- 1. memset W (32 MiB zero) ----------------
#define MS_BLOCKS 2048    // 2048*256 threads * 4 * 16B = 32 MiB
__global__ __launch_bounds__(256) void memset_w(uint4* __restrict__ Wb4) {
  const uint4 z = {0u, 0u, 0u, 0u};
  const int idx = blockIdx.x * 256 + threadIdx.x;
#pragma unroll
  for (int j = 0; j < 4; ++j) Wb4[idx + j * (MS_BLOCKS * 256)] = z;
}

// ------- 2. fused: scatter (blocks < SC_BLOCKS, latency-bound) +
//            transpose inputs f32[K][N] -> bf16 Bt[N][K] (BW-bound) ---------
#define SC_BLOCKS 6250    // 6250*256 == NNZ_
#define TR_BLOCKS 16384   // (4096/32)^2
__global__ __launch_bounds__(256) void scatter_transpose(
    const float* __restrict__ vals, const int* __restrict__ rows,
    const int* __restrict__ cols, uint32_t* __restrict__ W32,
    const float* __restrict__ in, ushort_t* __restrict__ out) {
  const int b = blockIdx.x;
  if (b < SC_BLOCKS) {
    // optimistic-zero CAS scatter into bf16 W (W freshly zeroed; most words
    // have a single writer -> first CAS succeeds without a pre-load)
    const int i = b * 256 + threadIdx.x;   // < NNZ_ exactly
    const size_t idx = (size_t)rows[i] * N_IN_ + cols[i];
    const float v = vals[i];
    uint32_t* p = &W32[idx >> 1];
    const bool hi = (idx & 1) != 0;
    uint32_t cur = 0u;
    while (true) {
      ushort_t h = hi ? (ushort_t)(cur >> 16) : (ushort_t)(cur & 0xFFFFu);
      ushort_t nh = f32_to_bf16(bf16_to_f32(h) + v);
      uint32_t nw = hi ? ((cur & 0x0000FFFFu) | ((uint32_t)nh << 16))
                       : ((cur & 0xFFFF0000u) | (uint32_t)nh);
      uint32_t got = atomicCAS(p, cur, nw);
      if (got == cur) break;
      cur = got;
    }
  } else {
    const int b2 = b - SC_BLOCKS;
    __shared__ float tile[32][33];
    const int bx = (b2 & 127) * 32;   // batch base
    const int by = (b2 >> 7) * 32;    // k base
    const int tx = threadIdx.x & 31, ty = threadIdx.x >> 5;
#pragma unroll
    for (int i = 0; i < 32; i += 8)
      tile[ty + i][tx] = in[(size_t)(by + ty + i) * BATCH_ + bx + tx];
    __syncthreads();
    // store 8B/lane: lane (sy,sx) writes out[bx+sy][by+4sx .. +3]
    const int sx = threadIdx.x & 7, sy = threadIdx.x >> 3;
    ushort4 u;
    u.x = f32_to_bf16(tile[4 * sx + 0][sy]);
    u.y = f32_to_bf16(tile[4 * sx + 1][sy]);
    u.z = f32_to_bf16(tile[4 * sx + 2][sy]);
    u.w = f32_to_bf16(tile[4 * sx + 3][sy]);
    *(ushort4*)&out[(size_t)(bx + sy) * N_IN_ + by + 4 * sx] = u;
  }
}

// ---------------- 3. 256x256 ring-4 GEMM (r5 schedule — empirical best) -----
// C[m][n] = relu(sum_k A[m][k]*Bt[n][k] + bias[m])
// Per tile: {aH reads | stage h0 | vmcnt(6) | barrier |
//            cluster1 | RA reads | stage h1 | cluster2 | barrier}
#define BM 256
#define BN 256
#define BK 32
#define KTILES 128            // 4096/32
#define TILE_BYTES 32768      // A 16K + B 16K
#define B_OFF 16384

__global__ __launch_bounds__(512, 2) void gemm_bias_relu(
    const ushort_t* __restrict__ A,    // bf16 [N_OUT][N_IN]
    const ushort_t* __restrict__ Bt,   // bf16 [BATCH][N_IN]
    const float* __restrict__ bias,    // [N_OUT]
    float* __restrict__ C) {           // f32 [N_OUT][BATCH]
  __shared__ __align__(16) char smem[4 * TILE_BYTES];  // 128 KiB

  const int tid  = threadIdx.x;
  const int wid  = tid >> 6;
  const int lane = tid & 63;

  // T1: XCD swizzle (nwg=256, 8 XCDs, bijective)
  const int bid = blockIdx.x;
  const int swz = (bid & 7) * 32 + (bid >> 3);
  const int brow = (swz >> 4) * BM;
  const int bcol = (swz & 15) * BN;

  const int wr = wid >> 2;        // 0..1 -> rows wr*128..+128
  const int wc = wid & 3;         // 0..3 -> cols wc*64..+64
  const int fr = lane & 15;
  const int k0slot = lane >> 4;   // 0..3

  // frag LDS byte offsets (T2 XOR swizzle: bits7-8 -> bits4-5, involution)
  int aoff[8], boff[4];
#pragma unroll
  for (int mi = 0; mi < 8; ++mi) {
    int off = (wr * 128 + mi * 16 + fr) * 64 + k0slot * 16;
    aoff[mi] = off ^ (((off >> 7) & 3) << 4);
  }
#pragma unroll
  for (int ni = 0; ni < 4; ++ni) {
    int off = (wc * 64 + ni * 16 + fr) * 64 + k0slot * 16;
    boff[ni] = off ^ (((off >> 7) & 3) << 4);
  }

  // staging: waves 0-3 -> A, 4-7 -> B; wave sw owns 1KB chunks 4sw..4sw+3,
  // 2 per half; pre-swizzled per-lane global source (rule #21)
  const bool isB = wid >= 4;
  const int sw = isB ? wid - 4 : wid;
  const int swzl = lane ^ ((lane >> 3) & 3);
  const int rowInChunk = swzl >> 2;
  const int kelem = (swzl & 3) * 8;
  const ushort_t* gsrc = isB ? Bt : A;
  const size_t laneRowBase =
      (size_t)((isB ? bcol : brow) + sw * 64 + rowInChunk) * N_IN_ + kelem;
  const int ldsOpBase = isB ? B_OFF : 0;

#define STAGE(p, i, t)                                                        \
  gload_lds16(gsrc + laneRowBase + (size_t)(2 * (p) + (i)) * 16 * N_IN_ +     \
                  (size_t)(t) * BK,                                           \
              smem + ((t) & 3) * TILE_BYTES + ldsOpBase +                     \
                  (4 * sw + 2 * (p) + (i)) * 1024)

  f32x4 acc[8][4] = {};
  short8 aE[4], bE[4], aO[4], bO[4], aH[4];  // aH: intra-tile only

  // prologue: stage tiles 0,1,2; wait tile 0; preload tile-0 lo frags
#pragma unroll
  for (int t = 0; t < 3; ++t) {
    STAGE(0, 0, t); STAGE(0, 1, t); STAGE(1, 0, t); STAGE(1, 1, t);
  }
  waitvm<8>();
  BARRIER();
#pragma unroll
  for (int j = 0; j < 4; ++j) {
    aE[j] = *(const short8*)(smem + aoff[j]);
    bE[j] = *(const short8*)(smem + B_OFF + boff[j]);
  }

// TILE: pre-barrier {aH reads (buf t) | stage h0(t+3) | vmcnt | barrier};
// then ONE region: cluster1(AL×BB) | RA reads(buf t+1) | stage h1(t+3) |
// cluster2(aH×BB); end barrier (ring reuse guard).
#define TILE(t, AL, BB, ALn, BBn, S_ON, VM, RA_ON)                            \
  do {                                                                        \
    const char* buf  = &smem[((t) & 3) * TILE_BYTES];                         \
    const char* bufn = &smem[(((t) + 1) & 3) * TILE_BYTES];                   \
    _Pragma("unroll") for (int j = 0; j < 4; ++j)                             \
        aH[j] = *(const short8*)(buf + aoff[j + 4]);                          \
    if (S_ON) { STAGE(0, 0, (t) + 3); STAGE(0, 1, (t) + 3); }                 \
    VM;                                                                       \
    BARRIER();                                                                \
    __builtin_amdgcn_s_setprio(1);                                            \
    _Pragma("unroll") for (int mi = 0; mi < 4; ++mi)                          \
        _Pragma("unroll") for (int ni = 0; ni < 4; ++ni)                      \
            acc[mi][ni] = mfma_bf16(AL[mi], BB[ni], acc[mi][ni]);             \
    __builtin_amdgcn_s_setprio(0);                                            \
    if (RA_ON) {                                                              \
      _Pragma("unroll") for (int j = 0; j < 4; ++j)                           \
          ALn[j] = *(const short8*)(bufn + aoff[j]);                          \
      _Pragma("unroll") for (int j = 0; j < 4; ++j)                           \
          BBn[j] = *(const short8*)(bufn + B_OFF + boff[j]);                  \
    }                                                                         \
    if (S_ON) { STAGE(1, 0, (t) + 3); STAGE(1, 1, (t) + 3); }                 \
    __builtin_amdgcn_s_setprio(1);                                            \
    _Pragma("unroll") for (int mi = 0; mi < 4; ++mi)                          \
        _Pragma("unroll") for (int ni = 0; ni < 4; ++ni)                      \
            acc[mi + 4][ni] = mfma_bf16(aH[mi], BB[ni], acc[mi + 4][ni]);     \
    __builtin_amdgcn_s_setprio(0);                                            \
    BARRIER();                                                                \
  } while (0)

  // main: tiles 0..123 in E/O pairs; peel 124-127 (stage stops, vmcnt 6/4/0)
  for (int t = 0; t < KTILES - 4; t += 2) {
    TILE(t,     aE, bE, aO, bO, 1, waitvm<6>(), 1);
    TILE(t + 1, aO, bO, aE, bE, 1, waitvm<6>(), 1);
  }
  TILE(KTILES - 4, aE, bE, aO, bO, 1, waitvm<6>(), 1);
  TILE(KTILES - 3, aO, bO, aE, bE, 0, waitvm<4>(), 1);
  TILE(KTILES - 2, aE, bE, aO, bO, 0, waitvm<0>(), 1);
  TILE(KTILES - 1, aO, bO, aE, bE, 0, (void)0,     0);

  // epilogue: C/D map col = lane&15, row = (lane>>4)*4 + reg
  const int r0 = brow + wr * 128 + k0slot * 4;
  const int c0 = bcol + wc * 64 + fr;
#pragma unroll
  for (int mi = 0; mi < 8; ++mi) {
#pragma unroll
    for (int r = 0; r < 4; ++r) {
      const int row = r0 + mi * 16 + r;
      const float b = bias[row];
#pragma unroll
      for (int ni = 0; ni < 4; ++ni) {
        float v = acc[mi][ni][r] + b;
        C[(size_t)row * BATCH_ + c0 + ni * 16] = v > 0.f ? v : 0.f;
      }
    }
  }
#undef TILE
#undef STAGE
}

extern "C" void kernel_launch(void* const* d_in, const int* in_sizes, int n_in,
                              void* d_out, int out_size, void* d_ws, size_t ws_size,
                              hipStream_t stream) {
  const float* inputs = (const float*)d_in[0];
  const float* values = (const float*)d_in[1];
  const float* biases = (const float*)d_in[2];
  const int*   rows   = (const int*)d_in[3];
  const int*   cols   = (const int*)d_in[4];
  float* out = (float*)d_out;

  // layout: [0,32M) bf16 W ; [32M,64M) bf16 in^T
  const size_t W_BF16_BYTES = (size_t)N_OUT_ * N_IN_ * 2;  // 32 MiB
  if (ws_size < 2 * W_BF16_BYTES) return;
  char* ws = (char*)d_ws;
  ushort_t* Wb = (ushort_t*)ws;
  ushort_t* Bt = (ushort_t*)(ws + W_BF16_BYTES);

  memset_w<<<MS_BLOCKS, 256, 0, stream>>>((uint4*)Wb);
  scatter_transpose<<<SC_BLOCKS + TR_BLOCKS, 256, 0, stream>>>(
      values, rows, cols, (uint32_t*)Wb, inputs, Bt);
  gemm_bias_relu<<<dim3(256), 512, 0, stream>>>(Wb, Bt, biases, out);
}

// Round 11
// 183.625 us; speedup vs baseline: 1.1697x; 1.0489x over previous
//
#include <hip/hip_runtime.h>
#include <stdint.h>

#define N_OUT_  4096
#define N_IN_   4096
#define BATCH_  4096
#define NNZ_    1600000

typedef unsigned short ushort_t;
typedef float  f32x4  __attribute__((ext_vector_type(4)));
typedef short  short8 __attribute__((ext_vector_type(8)));
typedef __bf16 bf16x8 __attribute__((ext_vector_type(8)));

// RNE f32 -> bf16
__device__ inline ushort_t f32_to_bf16(float f) {
  uint32_t u = __float_as_uint(f);
  uint32_t r = u + 0x7FFFu + ((u >> 16) & 1u);
  return (ushort_t)(r >> 16);
}
__device__ inline float bf16_to_f32(ushort_t h) {
  return __uint_as_float(((uint32_t)h) << 16);
}

// async global->LDS, 16B/lane; LDS dest wave-uniform base + lane*16 (linear)
__device__ inline void gload_lds16(const void* g, void* l) {
  __builtin_amdgcn_global_load_lds(
      (const __attribute__((address_space(1))) void*)g,
      (__attribute__((address_space(3))) void*)l,
      16, 0, 0);
}

__device__ inline f32x4 mfma_bf16(short8 a, short8 b, f32x4 c) {
  return __builtin_amdgcn_mfma_f32_16x16x32_bf16(
      __builtin_bit_cast(bf16x8, a), __builtin_bit_cast(bf16x8, b), c, 0, 0, 0);
}

#define BARRIER() asm volatile("s_barrier" ::: "memory")
template <int N> __device__ __forceinline__ void waitvm() {
  if constexpr (N == 8)      asm volatile("s_waitcnt vmcnt(8)" ::: "memory");
  else if constexpr (N == 6) asm volatile("s_waitcnt vmcnt(6)" ::: "memory");
  else if constexpr (N == 4) asm volatile("s_waitcnt vmcnt(4)" ::: "memory");
  else                       asm volatile("s_waitcnt vmcnt(0)" ::: "memory");
}

// ---------------- 1. memset W (32 MiB zero) ----------------
#define MS_BLOCKS 2048    // 2048*256 threads * 4 * 16B = 32 MiB
__global__ __launch_bounds__(256) void memset_w(uint4* __restrict__ Wb4) {
  const uint4 z = {0u, 0u, 0u, 0u};
  const int idx = blockIdx.x * 256 + threadIdx.x;
#pragma unroll
  for (int j = 0; j < 4; ++j) Wb4[idx + j * (MS_BLOCKS * 256)] = z;
}

// ------- 2. fused scatter + transpose, INTERLEAVED block types --------------
// period-5 pattern: b%5<3 -> scatter (latency-bound CAS), else 64x64 transpose
// (BW-bound) -- each CU co-schedules both regimes so CAS stalls are filled.
#define SC_TOTAL 6250         // 6250*256 == NNZ_
#define TR_TOTAL 4096         // (4096/64)^2
#define FUSED_BLOCKS 10420    // 2084 periods of 5 (3 scatter + 2 transpose)
__global__ __launch_bounds__(256) void scatter_transpose(
    const float* __restrict__ vals, const int* __restrict__ rows,
    const int* __restrict__ cols, uint32_t* __restrict__ W32,
    const float* __restrict__ in, ushort_t* __restrict__ out) {
  const int b = blockIdx.x;
  const int m = b % 5;
  if (m < 3) {
    const int sb = (b / 5) * 3 + m;
    if (sb >= SC_TOTAL) return;
    // optimistic-zero CAS scatter into bf16 W (W freshly zeroed; most words
    // have a single writer -> first CAS succeeds without a pre-load)
    const int i = sb * 256 + threadIdx.x;   // < NNZ_
    const size_t idx = (size_t)rows[i] * N_IN_ + cols[i];
    const float v = vals[i];
    uint32_t* p = &W32[idx >> 1];
    const bool hi = (idx & 1) != 0;
    uint32_t cur = 0u;
    while (true) {
      ushort_t h = hi ? (ushort_t)(cur >> 16) : (ushort_t)(cur & 0xFFFFu);
      ushort_t nh = f32_to_bf16(bf16_to_f32(h) + v);
      uint32_t nw = hi ? ((cur & 0x0000FFFFu) | ((uint32_t)nh << 16))
                       : ((cur & 0xFFFF0000u) | (uint32_t)nh);
      uint32_t got = atomicCAS(p, cur, nw);
      if (got == cur) break;
      cur = got;
    }
  } else {
    const int tb = (b / 5) * 2 + (m - 3);
    if (tb >= TR_TOTAL) return;
    // 64x64 tile transpose: in f32[K][BATCH] -> out bf16[BATCH][K]
    __shared__ float tile[64][65];           // [k-off][batch-off], +1 pad
    const int bx = (tb & 63) * 64;           // batch base
    const int by = (tb >> 6) * 64;           // k base
    const int t = threadIdx.x;
    const int lr = t >> 4;                   // 0..15
    const int lc = (t & 15) * 4;             // 0,4,..,60
#pragma unroll
    for (int p = 0; p < 4; ++p) {
      const int i = lr + 16 * p;
      *(float4*)&tile[i][lc] =
          *(const float4*)&in[(size_t)(by + i) * BATCH_ + bx + lc];
    }
    __syncthreads();
    const int s = t & 7;                     // k-segment (8 elems)
    const int j0 = t >> 3;                   // 0..31 batch row
#pragma unroll
    for (int q = 0; q < 2; ++q) {
      const int j = j0 + 32 * q;
      uint32_t w0, w1, w2, w3;
      w0 = (uint32_t)f32_to_bf16(tile[8 * s + 0][j]) |
           ((uint32_t)f32_to_bf16(tile[8 * s + 1][j]) << 16);
      w1 = (uint32_t)f32_to_bf16(tile[8 * s + 2][j]) |
           ((uint32_t)f32_to_bf16(tile[8 * s + 3][j]) << 16);
      w2 = (uint32_t)f32_to_bf16(tile[8 * s + 4][j]) |
           ((uint32_t)f32_to_bf16(tile[8 * s + 5][j]) << 16);
      w3 = (uint32_t)f32_to_bf16(tile[8 * s + 6][j]) |
           ((uint32_t)f32_to_bf16(tile[8 * s + 7][j]) << 16);
      uint4 w = {w0, w1, w2, w3};
      *(uint4*)&out[(size_t)(bx + j) * N_IN_ + by + 8 * s] = w;  // 16B aligned
    }
  }
}

// ---------------- 3. 256x256 ring-4 GEMM (r5 schedule — FROZEN) -------------
// C[m][n] = relu(sum_k A[m][k]*Bt[n][k] + bias[m])
// Per tile: {aH reads | stage h0 | vmcnt(6) | barrier |
//            cluster1 | RA reads | stage h1 | cluster2 | barrier}
#define BM 256
#define BN 256
#define BK 32
#define KTILES 128            // 4096/32
#define TILE_BYTES 32768      // A 16K + B 16K
#define B_OFF 16384

__global__ __launch_bounds__(512, 2) void gemm_bias_relu(
    const ushort_t* __restrict__ A,    // bf16 [N_OUT][N_IN]
    const ushort_t* __restrict__ Bt,   // bf16 [BATCH][N_IN]
    const float* __restrict__ bias,    // [N_OUT]
    float* __restrict__ C) {           // f32 [N_OUT][BATCH]
  __shared__ __align__(16) char smem[4 * TILE_BYTES];  // 128 KiB

  const int tid  = threadIdx.x;
  const int wid  = tid >> 6;
  const int lane = tid & 63;

  // T1: XCD swizzle (nwg=256, 8 XCDs, bijective)
  const int bid = blockIdx.x;
  const int swz = (bid & 7) * 32 + (bid >> 3);
  const int brow = (swz >> 4) * BM;
  const int bcol = (swz & 15) * BN;

  const int wr = wid >> 2;        // 0..1 -> rows wr*128..+128
  const int wc = wid & 3;         // 0..3 -> cols wc*64..+64
  const int fr = lane & 15;
  const int k0slot = lane >> 4;   // 0..3

  // frag LDS byte offsets (T2 XOR swizzle: bits7-8 -> bits4-5, involution)
  int aoff[8], boff[4];
#pragma unroll
  for (int mi = 0; mi < 8; ++mi) {
    int off = (wr * 128 + mi * 16 + fr) * 64 + k0slot * 16;
    aoff[mi] = off ^ (((off >> 7) & 3) << 4);
  }
#pragma unroll
  for (int ni = 0; ni < 4; ++ni) {
    int off = (wc * 64 + ni * 16 + fr) * 64 + k0slot * 16;
    boff[ni] = off ^ (((off >> 7) & 3) << 4);
  }

  // staging: waves 0-3 -> A, 4-7 -> B; wave sw owns 1KB chunks 4sw..4sw+3,
  // 2 per half; pre-swizzled per-lane global source (rule #21)
  const bool isB = wid >= 4;
  const int sw = isB ? wid - 4 : wid;
  const int swzl = lane ^ ((lane >> 3) & 3);
  const int rowInChunk = swzl >> 2;
  const int kelem = (swzl & 3) * 8;
  const ushort_t* gsrc = isB ? Bt : A;
  const size_t laneRowBase =
      (size_t)((isB ? bcol : brow) + sw * 64 + rowInChunk) * N_IN_ + kelem;
  const int ldsOpBase = isB ? B_OFF : 0;

#define STAGE(p, i, t)                                                        \
  gload_lds16(gsrc + laneRowBase + (size_t)(2 * (p) + (i)) * 16 * N_IN_ +     \
                  (size_t)(t) * BK,                                           \
              smem + ((t) & 3) * TILE_BYTES + ldsOpBase +                     \
                  (4 * sw + 2 * (p) + (i)) * 1024)

  f32x4 acc[8][4] = {};
  short8 aE[4], bE[4], aO[4], bO[4], aH[4];  // aH: intra-tile only

  // prologue: stage tiles 0,1,2; wait tile 0; preload tile-0 lo frags
#pragma unroll
  for (int t = 0; t < 3; ++t) {
    STAGE(0, 0, t); STAGE(0, 1, t); STAGE(1, 0, t); STAGE(1, 1, t);
  }
  waitvm<8>();
  BARRIER();
#pragma unroll
  for (int j = 0; j < 4; ++j) {
    aE[j] = *(const short8*)(smem + aoff[j]);
    bE[j] = *(const short8*)(smem + B_OFF + boff[j]);
  }

// TILE: pre-barrier {aH reads (buf t) | stage h0(t+3) | vmcnt | barrier};
// then ONE region: cluster1(AL×BB) | RA reads(buf t+1) | stage h1(t+3) |
// cluster2(aH×BB); end barrier (ring reuse guard).
#define TILE(t, AL, BB, ALn, BBn, S_ON, VM, RA_ON)                            \
  do {                                                                        \
    const char* buf  = &smem[((t) & 3) * TILE_BYTES];                         \
    const char* bufn = &smem[(((t) + 1) & 3) * TILE_BYTES];                   \
    _Pragma("unroll") for (int j = 0; j < 4; ++j)                             \
        aH[j] = *(const short8*)(buf + aoff[j + 4]);                          \
    if (S_ON) { STAGE(0, 0, (t) + 3); STAGE(0, 1, (t) + 3); }                 \
    VM;                                                                       \
    BARRIER();                                                                \
    __builtin_amdgcn_s_setprio(1);                                            \
    _Pragma("unroll") for (int mi = 0; mi < 4; ++mi)                          \
        _Pragma("unroll") for (int ni = 0; ni < 4; ++ni)                      \
            acc[mi][ni] = mfma_bf16(AL[mi], BB[ni], acc[mi][ni]);             \
    __builtin_amdgcn_s_setprio(0);                                            \
    if (RA_ON) {                                                              \
      _Pragma("unroll") for (int j = 0; j < 4; ++j)                           \
          ALn[j] = *(const short8*)(bufn + aoff[j]);                          \
      _Pragma("unroll") for (int j = 0; j < 4; ++j)                           \
          BBn[j] = *(const short8*)(bufn + B_OFF + boff[j]);                  \
    }                                                                         \
    if (S_ON) { STAGE(1, 0, (t) + 3); STAGE(1, 1, (t) + 3); }                 \
    __builtin_amdgcn_s_setprio(1);                                            \
    _Pragma("unroll") for (int mi = 0; mi < 4; ++mi)                          \
        _Pragma("unroll") for (int ni = 0; ni < 4; ++ni)                      \
            acc[mi + 4][ni] = mfma_bf16(aH[mi], BB[ni], acc[mi + 4][ni]);     \
    __builtin_amdgcn_s_setprio(0);                                            \
    BARRIER();                                                                \
  } while (0)

  // main: tiles 0..123 in E/O pairs; peel 124-127 (stage stops, vmcnt 6/4/0)
  for (int t = 0; t < KTILES - 4; t += 2) {
    TILE(t,     aE, bE, aO, bO, 1, waitvm<6>(), 1);
    TILE(t + 1, aO, bO, aE, bE, 1, waitvm<6>(), 1);
  }
  TILE(KTILES - 4, aE, bE, aO, bO, 1, waitvm<6>(), 1);
  TILE(KTILES - 3, aO, bO, aE, bE, 0, waitvm<4>(), 1);
  TILE(KTILES - 2, aE, bE, aO, bO, 0, waitvm<0>(), 1);
  TILE(KTILES - 1, aO, bO, aE, bE, 0, (void)0,     0);

  // epilogue: C/D map col = lane&15, row = (lane>>4)*4 + reg
  const int r0 = brow + wr * 128 + k0slot * 4;
  const int c0 = bcol + wc * 64 + fr;
#pragma unroll
  for (int mi = 0; mi < 8; ++mi) {
#pragma unroll
    for (int r = 0; r < 4; ++r) {
      const int row = r0 + mi * 16 + r;
      const float b = bias[row];
#pragma unroll
      for (int ni = 0; ni < 4; ++ni) {
        float v = acc[mi][ni][r] + b;
        C[(size_t)row * BATCH_ + c0 + ni * 16] = v > 0.f ? v : 0.f;
      }
    }
  }
#undef TILE
#undef STAGE
}

extern "C" void kernel_launch(void* const* d_in, const int* in_sizes, int n_in,
                              void* d_out, int out_size, void* d_ws, size_t ws_size,
                              hipStream_t stream) {
  const float* inputs = (const float*)d_in[0];
  const float* values = (const float*)d_in[1];
  const float* biases = (const float*)d_in[2];
  const int*   rows   = (const int*)d_in[3];
  const int*   cols   = (const int*)d_in[4];
  float* out = (float*)d_out;

  // layout: [0,32M) bf16 W ; [32M,64M) bf16 in^T
  const size_t W_BF16_BYTES = (size_t)N_OUT_ * N_IN_ * 2;  // 32 MiB
  if (ws_size < 2 * W_BF16_BYTES) return;
  char* ws = (char*)d_ws;
  ushort_t* Wb = (ushort_t*)ws;
  ushort_t* Bt = (ushort_t*)(ws + W_BF16_BYTES);

  memset_w<<<MS_BLOCKS, 256, 0, stream>>>((uint4*)Wb);
  scatter_transpose<<<FUSED_BLOCKS, 256, 0, stream>>>(
      values, rows, cols, (uint32_t*)Wb, inputs, Bt);
  gemm_bias_relu<<<dim3(256), 512, 0, stream>>>(Wb, Bt, biases, out);
}

// Round 12
// 182.958 us; speedup vs baseline: 1.1740x; 1.0036x over previous
//
#include <hip/hip_runtime.h>
#include <stdint.h>

#define N_OUT_  4096
#define N_IN_   4096
#define BATCH_  4096
#define NNZ_    1600000

typedef unsigned short ushort_t;
typedef float  f32x4  __attribute__((ext_vector_type(4)));
typedef short  short8 __attribute__((ext_vector_type(8)));
typedef __bf16 bf16x8 __attribute__((ext_vector_type(8)));

// RNE f32 -> bf16
__device__ inline ushort_t f32_to_bf16(float f) {
  uint32_t u = __float_as_uint(f);
  uint32_t r = u + 0x7FFFu + ((u >> 16) & 1u);
  return (ushort_t)(r >> 16);
}
__device__ inline float bf16_to_f32(ushort_t h) {
  return __uint_as_float(((uint32_t)h) << 16);
}

// async global->LDS, 16B/lane; LDS dest wave-uniform base + lane*16 (linear)
__device__ inline void gload_lds16(const void* g, void* l) {
  __builtin_amdgcn_global_load_lds(
      (const __attribute__((address_space(1))) void*)g,
      (__attribute__((address_space(3))) void*)l,
      16, 0, 0);
}

__device__ inline f32x4 mfma_bf16(short8 a, short8 b, f32x4 c) {
  return __builtin_amdgcn_mfma_f32_16x16x32_bf16(
      __builtin_bit_cast(bf16x8, a), __builtin_bit_cast(bf16x8, b), c, 0, 0, 0);
}

#define BARRIER() asm volatile("s_barrier" ::: "memory")
template <int N> __device__ __forceinline__ void waitvm() {
  if constexpr (N == 8)      asm volatile("s_waitcnt vmcnt(8)" ::: "memory");
  else if constexpr (N == 6) asm volatile("s_waitcnt vmcnt(6)" ::: "memory");
  else if constexpr (N == 4) asm volatile("s_waitcnt vmcnt(4)" ::: "memory");
  else                       asm volatile("s_waitcnt vmcnt(0)" ::: "memory");
}

// ------- fused scatter (2 indep CAS chains/thread) + 64x64 transpose --------
// period-7: b%7<3 -> scatter, else transpose; co-schedules latency-bound CAS
// with BW-bound transpose on every CU.
#define SC_BLOCKS2 3125       // 3125*256*2 == NNZ_
#define TR_TOTAL 4096         // (4096/64)^2
#define FUSED_BLOCKS 7294     // 1042 periods of 7 (3 scatter + 4 transpose)
#define HALF_NNZ 800000

__device__ inline void cas_add_bf16(uint32_t* __restrict__ W32, int i,
                                    const float* __restrict__ vals,
                                    const int* __restrict__ rows,
                                    const int* __restrict__ cols) {
  const size_t idx =
      (size_t)__builtin_nontemporal_load(rows + i) * N_IN_ +
      __builtin_nontemporal_load(cols + i);
  const float v = __builtin_nontemporal_load(vals + i);
  uint32_t* p = &W32[idx >> 1];
  const bool hi = (idx & 1) != 0;
  uint32_t cur = 0u;   // optimistic: W freshly zeroed
  while (true) {
    ushort_t h = hi ? (ushort_t)(cur >> 16) : (ushort_t)(cur & 0xFFFFu);
    ushort_t nh = f32_to_bf16(bf16_to_f32(h) + v);
    uint32_t nw = hi ? ((cur & 0x0000FFFFu) | ((uint32_t)nh << 16))
                     : ((cur & 0xFFFF0000u) | (uint32_t)nh);
    uint32_t got = atomicCAS(p, cur, nw);
    if (got == cur) break;
    cur = got;
  }
}

__global__ __launch_bounds__(256) void scatter_transpose(
    const float* __restrict__ vals, const int* __restrict__ rows,
    const int* __restrict__ cols, uint32_t* __restrict__ W32,
    const float* __restrict__ in, ushort_t* __restrict__ out) {
  const int b = blockIdx.x;
  const int m = b % 7;
  if (m < 3) {
    const int sb = (b / 7) * 3 + m;
    if (sb >= SC_BLOCKS2) return;
    const int i = sb * 256 + threadIdx.x;           // < 800000
    cas_add_bf16(W32, i, vals, rows, cols);         // chain 1
    cas_add_bf16(W32, i + HALF_NNZ, vals, rows, cols);  // chain 2 (indep)
  } else {
    const int tb = (b / 7) * 4 + (m - 3);
    if (tb >= TR_TOTAL) return;
    // 64x64 tile transpose: in f32[K][BATCH] -> out bf16[BATCH][K]
    __shared__ float tile[64][65];           // +1 pad
    const int bx = (tb & 63) * 64;           // batch base
    const int by = (tb >> 6) * 64;           // k base
    const int t = threadIdx.x;
    const int lr = t >> 4;                   // 0..15
    const int lc = (t & 15) * 4;             // 0,4,..,60
#pragma unroll
    for (int p = 0; p < 4; ++p) {
      const int i = lr + 16 * p;
      *(float4*)&tile[i][lc] =
          *(const float4*)&in[(size_t)(by + i) * BATCH_ + bx + lc];
    }
    __syncthreads();
    const int s = t & 7;                     // k-segment (8 elems)
    const int j0 = t >> 3;                   // 0..31 batch row
#pragma unroll
    for (int q = 0; q < 2; ++q) {
      const int j = j0 + 32 * q;
      uint32_t w0, w1, w2, w3;
      w0 = (uint32_t)f32_to_bf16(tile[8 * s + 0][j]) |
           ((uint32_t)f32_to_bf16(tile[8 * s + 1][j]) << 16);
      w1 = (uint32_t)f32_to_bf16(tile[8 * s + 2][j]) |
           ((uint32_t)f32_to_bf16(tile[8 * s + 3][j]) << 16);
      w2 = (uint32_t)f32_to_bf16(tile[8 * s + 4][j]) |
           ((uint32_t)f32_to_bf16(tile[8 * s + 5][j]) << 16);
      w3 = (uint32_t)f32_to_bf16(tile[8 * s + 6][j]) |
           ((uint32_t)f32_to_bf16(tile[8 * s + 7][j]) << 16);
      uint4 w = {w0, w1, w2, w3};
      *(uint4*)&out[(size_t)(bx + j) * N_IN_ + by + 8 * s] = w;
    }
  }
}

// ---------------- 256x256 ring-4 GEMM (r5 schedule — FROZEN) ----------------
#define BM 256
#define BN 256
#define BK 32
#define KTILES 128
#define TILE_BYTES 32768
#define B_OFF 16384

__global__ __launch_bounds__(512, 2) void gemm_bias_relu(
    const ushort_t* __restrict__ A,
    const ushort_t* __restrict__ Bt,
    const float* __restrict__ bias,
    float* __restrict__ C) {
  __shared__ __align__(16) char smem[4 * TILE_BYTES];

  const int tid  = threadIdx.x;
  const int wid  = tid >> 6;
  const int lane = tid & 63;

  const int bid = blockIdx.x;
  const int swz = (bid & 7) * 32 + (bid >> 3);
  const int brow = (swz >> 4) * BM;
  const int bcol = (swz & 15) * BN;

  const int wr = wid >> 2;
  const int wc = wid & 3;
  const int fr = lane & 15;
  const int k0slot = lane >> 4;

  int aoff[8], boff[4];
#pragma unroll
  for (int mi = 0; mi < 8; ++mi) {
    int off = (wr * 128 + mi * 16 + fr) * 64 + k0slot * 16;
    aoff[mi] = off ^ (((off >> 7) & 3) << 4);
  }
#pragma unroll
  for (int ni = 0; ni < 4; ++ni) {
    int off = (wc * 64 + ni * 16 + fr) * 64 + k0slot * 16;
    boff[ni] = off ^ (((off >> 7) & 3) << 4);
  }

  const bool isB = wid >= 4;
  const int sw = isB ? wid - 4 : wid;
  const int swzl = lane ^ ((lane >> 3) & 3);
  const int rowInChunk = swzl >> 2;
  const int kelem = (swzl & 3) * 8;
  const ushort_t* gsrc = isB ? Bt : A;
  const size_t laneRowBase =
      (size_t)((isB ? bcol : brow) + sw * 64 + rowInChunk) * N_IN_ + kelem;
  const int ldsOpBase = isB ? B_OFF : 0;

#define STAGE(p, i, t)                                                        \
  gload_lds16(gsrc + laneRowBase + (size_t)(2 * (p) + (i)) * 16 * N_IN_ +     \
                  (size_t)(t) * BK,                                           \
              smem + ((t) & 3) * TILE_BYTES + ldsOpBase +                     \
                  (4 * sw + 2 * (p) + (i)) * 1024)

  f32x4 acc[8][4] = {};
  short8 aE[4], bE[4], aO[4], bO[4], aH[4];

#pragma unroll
  for (int t = 0; t < 3; ++t) {
    STAGE(0, 0, t); STAGE(0, 1, t); STAGE(1, 0, t); STAGE(1, 1, t);
  }
  waitvm<8>();
  BARRIER();
#pragma unroll
  for (int j = 0; j < 4; ++j) {
    aE[j] = *(const short8*)(smem + aoff[j]);
    bE[j] = *(const short8*)(smem + B_OFF + boff[j]);
  }

#define TILE(t, AL, BB, ALn, BBn, S_ON, VM, RA_ON)                            \
  do {                                                                        \
    const char* buf  = &smem[((t) & 3) * TILE_BYTES];                         \
    const char* bufn = &smem[(((t) + 1) & 3) * TILE_BYTES];                   \
    _Pragma("unroll") for (int j = 0; j < 4; ++j)                             \
        aH[j] = *(const short8*)(buf + aoff[j + 4]);                          \
    if (S_ON) { STAGE(0, 0, (t) + 3); STAGE(0, 1, (t) + 3); }                 \
    VM;                                                                       \
    BARRIER();                                                                \
    __builtin_amdgcn_s_setprio(1);                                            \
    _Pragma("unroll") for (int mi = 0; mi < 4; ++mi)                          \
        _Pragma("unroll") for (int ni = 0; ni < 4; ++ni)                      \
            acc[mi][ni] = mfma_bf16(AL[mi], BB[ni], acc[mi][ni]);             \
    __builtin_amdgcn_s_setprio(0);                                            \
    if (RA_ON) {                                                              \
      _Pragma("unroll") for (int j = 0; j < 4; ++j)                           \
          ALn[j] = *(const short8*)(bufn + aoff[j]);                          \
      _Pragma("unroll") for (int j = 0; j < 4; ++j)                           \
          BBn[j] = *(const short8*)(bufn + B_OFF + boff[j]);                  \
    }                                                                         \
    if (S_ON) { STAGE(1, 0, (t) + 3); STAGE(1, 1, (t) + 3); }                 \
    __builtin_amdgcn_s_setprio(1);                                            \
    _Pragma("unroll") for (int mi = 0; mi < 4; ++mi)                          \
        _Pragma("unroll") for (int ni = 0; ni < 4; ++ni)                      \
            acc[mi + 4][ni] = mfma_bf16(aH[mi], BB[ni], acc[mi + 4][ni]);     \
    __builtin_amdgcn_s_setprio(0);                                            \
    BARRIER();                                                                \
  } while (0)

  for (int t = 0; t < KTILES - 4; t += 2) {
    TILE(t,     aE, bE, aO, bO, 1, waitvm<6>(), 1);
    TILE(t + 1, aO, bO, aE, bE, 1, waitvm<6>(), 1);
  }
  TILE(KTILES - 4, aE, bE, aO, bO, 1, waitvm<6>(), 1);
  TILE(KTILES - 3, aO, bO, aE, bE, 0, waitvm<4>(), 1);
  TILE(KTILES - 2, aE, bE, aO, bO, 0, waitvm<0>(), 1);
  TILE(KTILES - 1, aO, bO, aE, bE, 0, (void)0,     0);

  const int r0 = brow + wr * 128 + k0slot * 4;
  const int c0 = bcol + wc * 64 + fr;
#pragma unroll
  for (int mi = 0; mi < 8; ++mi) {
#pragma unroll
    for (int r = 0; r < 4; ++r) {
      const int row = r0 + mi * 16 + r;
      const float b = bias[row];
#pragma unroll
      for (int ni = 0; ni < 4; ++ni) {
        float v = acc[mi][ni][r] + b;
        C[(size_t)row * BATCH_ + c0 + ni * 16] = v > 0.f ? v : 0.f;
      }
    }
  }
#undef TILE
#undef STAGE
}

extern "C" void kernel_launch(void* const* d_in, const int* in_sizes, int n_in,
                              void* d_out, int out_size, void* d_ws, size_t ws_size,
                              hipStream_t stream) {
  const float* inputs = (const float*)d_in[0];
  const float* values = (const float*)d_in[1];
  const float* biases = (const float*)d_in[2];
  const int*   rows   = (const int*)d_in[3];
  const int*   cols   = (const int*)d_in[4];
  float* out = (float*)d_out;

  // layout: [0,32M) bf16 W ; [32M,64M) bf16 in^T
  const size_t W_BF16_BYTES = (size_t)N_OUT_ * N_IN_ * 2;  // 32 MiB
  if (ws_size < 2 * W_BF16_BYTES) return;
  char* ws = (char*)d_ws;
  ushort_t* Wb = (ushort_t*)ws;
  ushort_t* Bt = (ushort_t*)(ws + W_BF16_BYTES);

  hipMemsetAsync(Wb, 0, W_BF16_BYTES, stream);
  scatter_transpose<<<FUSED_BLOCKS, 256, 0, stream>>>(
      values, rows, cols, (uint32_t*)Wb, inputs, Bt);
  gemm_bias_relu<<<dim3(256), 512, 0, stream>>>(Wb, Bt, biases, out);
}